// Round 13
// baseline (706.257 us; speedup 1.0000x reference)
//
#include <hip/hip_runtime.h>
#include <stdint.h>

#define NB 2048
#define OBSD 256
#define POP 10
#define NIN 2560       // OBS_DIM * POP_DIM
#define H 256          // HID1 == HID2
#define OUTP 80        // ACT_DIM * DE_POP
#define TS 25
#define RECF 28        // floats per row record (25 bit-floats + 3 pad, 112 B)

typedef __attribute__((ext_vector_type(2))) float f32x2;

// correctly-rounded fp32 exp (fp64 exp then round) — matches SVML high-accuracy
// expf that numpy dispatches to on AVX512 hosts (validated r8: absmax 4.8e-7).
__device__ __forceinline__ float exp_cr(float x) {
    return (float)exp((double)x);
}

__device__ __forceinline__ int rfl(int v) {
    return __builtin_amdgcn_readfirstlane(v);
}

// ---------------- K0: transpose weights into fp32 [k][n] layouts in ws ----------------
__global__ __launch_bounds__(256) void k0_transpose(
    const float* __restrict__ w1, const float* __restrict__ w2, const float* __restrict__ w3,
    float* __restrict__ w1t, float* __restrict__ w2t, float* __restrict__ w3t)
{
    int idx = blockIdx.x * 256 + threadIdx.x;
    const int N1 = NIN * H;       // 655360
    const int N2 = H * H;         // 65536
    const int N3 = H * OUTP;      // 20480
    if (idx < N1) {
        int i = idx >> 8, j = idx & 255;
        w1t[idx] = w1[j * NIN + i];
    } else if (idx < N1 + N2) {
        int k = idx - N1;
        int i = k >> 8, j = k & 255;
        w2t[k] = w2[j * H + i];
    } else if (idx < N1 + N2 + N3) {
        int k = idx - N1 - N2;
        int i = k / OUTP, j = k - i * OUTP;
        w3t[k] = w3[j * H + i];
    }
}

// One LIF step, numpy-faithful per-op rounding (no contraction):
__device__ __forceinline__ void lif_step(float x, float bv, float& c, float& v, float& s) {
    float cn = __fadd_rn(__fadd_rn(__fmul_rn(c, 0.5f), x), bv);
    c = cn;
    float vp = v;
    float t  = __fmul_rn(__fmul_rn(vp, 0.75f), __fadd_rn(1.0f, -s));
    float vn = __fadd_rn(t, cn);
    float ag = __fdiv_rn(__fadd_rn(vp, -vn), 3.0f);
    float ex = exp_cr(ag);
    float vth = __fadd_rn(0.25f, __fmul_rn(0.5f, __fadd_rn(ex, -1.0f)));
    v = vn;
    s = (vn > vth) ? 1.0f : 0.0f;
}

// write one row record: 25 spike bits as floats {0.0,1.0} + 3 pad (7 float4s)
__device__ __forceinline__ void write_rec(float* __restrict__ pairL, int pos, uint32_t m) {
    float f[RECF];
    #pragma unroll
    for (int t = 0; t < TS; ++t) f[t] = (m >> t) & 1u ? 1.0f : 0.0f;
    f[25] = 0.0f; f[26] = 0.0f; f[27] = 0.0f;
    float4* dst = (float4*)&pairL[pos * RECF];
    #pragma unroll
    for (int p = 0; p < 7; ++p)
        dst[p] = make_float4(f[4 * p], f[4 * p + 1], f[4 * p + 2], f[4 * p + 3]);
}

// 25-term fma chain via packed fp32 FMA (v_pk_fma_f32 = two independent IEEE
// fp32 fmas per inst — per-lane bitwise == 25 scalar fmaf == BLAS fma(w,s,acc))
__device__ __forceinline__ void fma25(float w, const float* __restrict__ rec,
                                      float* __restrict__ acc) {
    f32x2 wp = {w, w};
    #pragma unroll
    for (int p = 0; p < 12; ++p) {
        f32x2 r = *(const f32x2*)&rec[2 * p];
        f32x2 a = {acc[2 * p], acc[2 * p + 1]};
        asm("v_pk_fma_f32 %0, %1, %2, %0" : "+v"(a) : "v"(wp), "v"(r));
        acc[2 * p] = a.x; acc[2 * p + 1] = a.y;
    }
    acc[24] = fmaf(w, rec[24], acc[24]);
}

// ---------------- K1: fused, ONE batch row per block (2048 blocks) ----------------
__global__ __launch_bounds__(256, 4) void k1_fused(
    const float* __restrict__ obs, const float* __restrict__ emean, const float* __restrict__ estd,
    const float* __restrict__ w1t, const float* __restrict__ w2t, const float* __restrict__ w3t,
    const float* __restrict__ b1, const float* __restrict__ b2, const float* __restrict__ b3,
    const float* __restrict__ dw, const float* __restrict__ db, float* __restrict__ out)
{
    __shared__ __align__(16) float pairL[256 * RECF];  // 28,672 B row records
    __shared__ __align__(16) int   idxL[256];          //  1,024 B premult indices
    __shared__ uint32_t waveCnt[4];
    __shared__ float cnt3[OUTP];

    const int tid = threadIdx.x;
    const int wave = tid >> 6, lane = tid & 63;
    const int b = blockIdx.x;
    const unsigned long long below = (1ull << lane) - 1ull;

    // ---- Phase A: population encoding, numpy-faithful fp32 op-by-op ----
    uint32_t msk[10];
    #pragma unroll
    for (int k = 0; k < 10; ++k) {
        int i = k * 256 + tid;
        int o = i / 10;
        float x  = obs[b * OBSD + o];
        float mu = emean[i];
        float sd = estd[i];
        float d  = __fadd_rn(x, -mu);
        float d2 = __fmul_rn(d, d);
        float nm = __fmul_rn(-0.5f, d2);
        float dn = __fmul_rn(sd, sd);
        float a  = exp_cr(__fdiv_rn(nm, dn));
        float volt = 0.0f;
        uint32_t m = 0;
        #pragma unroll
        for (int t = 0; t < TS; ++t) {
            volt = __fadd_rn(volt, a);
            if (volt > 0.999f) { m |= (1u << t); volt = __fadd_rn(volt, -0.999f); }
        }
        msk[k] = m;
    }

    // ---- Phase B: event GEMM1 in two halves (<=256 active rows per half).
    // K-blocks {320 x 8} left-assoc via sorted-index boundary folds (r8-valid). ----
    float acc[TS], part[TS];
    #pragma unroll
    for (int t = 0; t < TS; ++t) { acc[t] = 0.0f; part[t] = 0.0f; }
    int nextB = 320 * H;

    for (int h = 0; h < 2; ++h) {
        // build compacted records (ascending i) for this half
        int runTot = 0;
        for (int kk = 0; kk < 5; ++kk) {
            int k = h * 5 + kk;
            uint32_t m = msk[k];
            unsigned long long bal = __ballot(m != 0u);
            if (lane == 0) waveCnt[wave] = (uint32_t)__popcll(bal);
            __syncthreads();
            int base = runTot, tot = 0;
            #pragma unroll
            for (int w = 0; w < 4; ++w) {
                if (w < wave) base += (int)waveCnt[w];
                tot += (int)waveCnt[w];
            }
            if (m) {
                int pos = base + (int)__popcll(bal & below);
                idxL[pos] = (k * 256 + tid) * H;
                write_rec(pairL, pos, m);
            }
            runTot += tot;
            __syncthreads();
        }
        const int nAct = runTot;

        // walk with 4-deep weight prefetch ring; 25-fma chain per row
        int ibuf[4]; float wbuf[4];
        #pragma unroll
        for (int p = 0; p < 4; ++p) {
            if (p < nAct) { ibuf[p] = rfl(idxL[p]); wbuf[p] = w1t[ibuf[p] + tid]; }
        }
        for (int j = 0; j < nAct; ++j) {
            int slot = j & 3;
            int idxCur = ibuf[slot];
            float wCur = wbuf[slot];
            int jn = j + 4;
            if (jn < nAct) { int ii = rfl(idxL[jn]); ibuf[slot] = ii; wbuf[slot] = w1t[ii + tid]; }
            while (idxCur >= nextB) {       // K-block boundary fold
                #pragma unroll
                for (int t = 0; t < TS; ++t) {
                    acc[t] = __fadd_rn(acc[t], part[t]);
                    part[t] = 0.0f;
                }
                nextB += 320 * H;
            }
            fma25(wCur, &pairL[j * RECF], part);
        }
        __syncthreads();   // records dead; next half (or C1 build) may overwrite
    }
    // final fold (remaining partial; empty trailing blocks are exact no-ops)
    #pragma unroll
    for (int t = 0; t < TS; ++t) acc[t] = __fadd_rn(acc[t], part[t]);

    // ---- C1: layer-1 LIF, all 25 steps; build layer-1 spike records ----
    uint32_t m1 = 0;
    {
        const float b1v = b1[tid];
        float c1 = 0, v1 = 0, s1 = 0;
        #pragma unroll
        for (int t = 0; t < TS; ++t) {
            lif_step(acc[t], b1v, c1, v1, s1);
            if (s1 != 0.0f) m1 |= (1u << t);
        }
    }
    unsigned long long bal = __ballot(m1 != 0u);
    if (lane == 0) waveCnt[wave] = (uint32_t)__popcll(bal);
    __syncthreads();
    int base1 = 0, n1 = 0;
    #pragma unroll
    for (int w = 0; w < 4; ++w) {
        if (w < wave) base1 += (int)waveCnt[w];
        n1 += (int)waveCnt[w];
    }
    if (m1) {
        int pos = base1 + (int)__popcll(bal & below);
        idxL[pos] = tid * H;
        write_rec(pairL, pos, m1);
    }
    __syncthreads();

    // ---- C2: batched GEMM2 walk (K=256, single block) + layer-2 LIF ----
    float acc2[TS];
    #pragma unroll
    for (int t = 0; t < TS; ++t) acc2[t] = 0.0f;
    {
        int ibuf[4]; float wbuf[4];
        #pragma unroll
        for (int p = 0; p < 4; ++p) {
            if (p < n1) { ibuf[p] = rfl(idxL[p]); wbuf[p] = w2t[ibuf[p] + tid]; }
        }
        for (int j = 0; j < n1; ++j) {
            int slot = j & 3;
            float wCur = wbuf[slot];
            int jn = j + 4;
            if (jn < n1) { int ii = rfl(idxL[jn]); ibuf[slot] = ii; wbuf[slot] = w2t[ii + tid]; }
            fma25(wCur, &pairL[j * RECF], acc2);
        }
    }
    uint32_t m2 = 0;
    {
        const float b2v = b2[tid];
        float c2 = 0, v2 = 0, s2 = 0;
        #pragma unroll
        for (int t = 0; t < TS; ++t) {
            lif_step(acc2[t], b2v, c2, v2, s2);
            if (s2 != 0.0f) m2 |= (1u << t);
        }
    }
    __syncthreads();   // C2 walk reads done before list-2 build overwrites
    bal = __ballot(m2 != 0u);
    if (lane == 0) waveCnt[wave] = (uint32_t)__popcll(bal);
    __syncthreads();
    int base2 = 0, n2 = 0;
    #pragma unroll
    for (int w = 0; w < 4; ++w) {
        if (w < wave) base2 += (int)waveCnt[w];
        n2 += (int)waveCnt[w];
    }
    if (m2) {
        int pos = base2 + (int)__popcll(bal & below);
        idxL[pos] = tid * OUTP;
        write_rec(pairL, pos, m2);
    }
    __syncthreads();

    // ---- C3: batched GEMM3 walk + layer-3 LIF (threads 0..79) ----
    if (tid < OUTP) {
        float x3[TS];
        #pragma unroll
        for (int t = 0; t < TS; ++t) x3[t] = 0.0f;
        int ibuf[4]; float wbuf[4];
        #pragma unroll
        for (int p = 0; p < 4; ++p) {
            if (p < n2) { ibuf[p] = rfl(idxL[p]); wbuf[p] = w3t[ibuf[p] + tid]; }
        }
        for (int j = 0; j < n2; ++j) {
            int slot = j & 3;
            float wCur = wbuf[slot];
            int jn = j + 4;
            if (jn < n2) { int ii = rfl(idxL[jn]); ibuf[slot] = ii; wbuf[slot] = w3t[ii + tid]; }
            fma25(wCur, &pairL[j * RECF], x3);
        }
        const float b3v = b3[tid];
        float c3 = 0, v3 = 0, s3 = 0, ct = 0;
        #pragma unroll
        for (int t = 0; t < TS; ++t) {
            lif_step(x3[t], b3v, c3, v3, s3);
            ct += s3;
        }
        cnt3[tid] = ct;
    }
    __syncthreads();

    // ---- decode: per-op rounding like np einsum (no FMA) ----
    if (tid < 8) {
        float raw = 0.0f;
        #pragma unroll
        for (int pp = 0; pp < POP; ++pp) {
            float po = __fdiv_rn(cnt3[tid * POP + pp], 25.0f);
            raw = __fadd_rn(raw, __fmul_rn(po, dw[tid * POP + pp]));
        }
        raw = __fadd_rn(raw, db[tid]);
        out[b * 8 + tid] = (float)tanh((double)raw);
    }
}

extern "C" void kernel_launch(void* const* d_in, const int* in_sizes, int n_in,
                              void* d_out, int out_size, void* d_ws, size_t ws_size,
                              hipStream_t stream) {
    const float* obs   = (const float*)d_in[0];
    const float* emean = (const float*)d_in[1];
    const float* estd  = (const float*)d_in[2];
    const float* w1    = (const float*)d_in[3];
    const float* b1    = (const float*)d_in[4];
    const float* w2    = (const float*)d_in[5];
    const float* b2    = (const float*)d_in[6];
    const float* w3    = (const float*)d_in[7];
    const float* b3    = (const float*)d_in[8];
    const float* dw    = (const float*)d_in[9];
    const float* db    = (const float*)d_in[10];
    float* out = (float*)d_out;

    char* ws = (char*)d_ws;
    float* w1t = (float*)(ws);                 // 655360 * 4 = 2,621,440 B
    float* w2t = (float*)(ws + 2621440);       //  65536 * 4 =   262,144 B
    float* w3t = (float*)(ws + 2883584);       //  20480 * 4 =    81,920 B

    k0_transpose<<<2896, 256, 0, stream>>>(w1, w2, w3, w1t, w2t, w3t);
    k1_fused<<<NB, 256, 0, stream>>>(obs, emean, estd, w1t, w2t, w3t,
                                     b1, b2, b3, dw, db, out);
}

// Round 14
// 547.204 us; speedup vs baseline: 1.2907x; 1.2907x over previous
//
#include <hip/hip_runtime.h>
#include <stdint.h>

#define NB 2048
#define OBSD 256
#define POP 10
#define NIN 2560       // OBS_DIM * POP_DIM
#define H 256          // HID1 == HID2
#define OUTP 80        // ACT_DIM * DE_POP
#define TS 25
#define RECF 28        // floats per row record (25 bit-floats + 3 pad, 112 B)

// correctly-rounded fp32 exp (fp64 exp then round) — matches SVML high-accuracy
// expf that numpy dispatches to on AVX512 hosts (validated r8: absmax 4.8e-7).
__device__ __forceinline__ float exp_cr(float x) {
    return (float)exp((double)x);
}

__device__ __forceinline__ int rfl(int v) {
    return __builtin_amdgcn_readfirstlane(v);
}

// ---------------- K0: transpose weights into fp32 [k][n] layouts in ws ----------------
__global__ __launch_bounds__(256) void k0_transpose(
    const float* __restrict__ w1, const float* __restrict__ w2, const float* __restrict__ w3,
    float* __restrict__ w1t, float* __restrict__ w2t, float* __restrict__ w3t)
{
    int idx = blockIdx.x * 256 + threadIdx.x;
    const int N1 = NIN * H;       // 655360
    const int N2 = H * H;         // 65536
    const int N3 = H * OUTP;      // 20480
    if (idx < N1) {
        int i = idx >> 8, j = idx & 255;
        w1t[idx] = w1[j * NIN + i];
    } else if (idx < N1 + N2) {
        int k = idx - N1;
        int i = k >> 8, j = k & 255;
        w2t[k] = w2[j * H + i];
    } else if (idx < N1 + N2 + N3) {
        int k = idx - N1 - N2;
        int i = k / OUTP, j = k - i * OUTP;
        w3t[k] = w3[j * H + i];
    }
}

// One LIF step, numpy-faithful per-op rounding (no contraction):
__device__ __forceinline__ void lif_step(float x, float bv, float& c, float& v, float& s) {
    float cn = __fadd_rn(__fadd_rn(__fmul_rn(c, 0.5f), x), bv);
    c = cn;
    float vp = v;
    float t  = __fmul_rn(__fmul_rn(vp, 0.75f), __fadd_rn(1.0f, -s));
    float vn = __fadd_rn(t, cn);
    float ag = __fdiv_rn(__fadd_rn(vp, -vn), 3.0f);
    float ex = exp_cr(ag);
    float vth = __fadd_rn(0.25f, __fmul_rn(0.5f, __fadd_rn(ex, -1.0f)));
    v = vn;
    s = (vn > vth) ? 1.0f : 0.0f;
}

// write one row record: 25 spike bits as floats {0.0,1.0} + 3 pad (7 float4s)
__device__ __forceinline__ void write_rec(float* __restrict__ pairL, int pos, uint32_t m) {
    float f[RECF];
    #pragma unroll
    for (int t = 0; t < TS; ++t) f[t] = (m >> t) & 1u ? 1.0f : 0.0f;
    f[25] = 0.0f; f[26] = 0.0f; f[27] = 0.0f;
    float4* dst = (float4*)&pairL[pos * RECF];
    #pragma unroll
    for (int p = 0; p < 7; ++p)
        dst[p] = make_float4(f[4 * p], f[4 * p + 1], f[4 * p + 2], f[4 * p + 3]);
}

// 25-term fma chain: acc[t] = fma(w, bit[t], acc[t])  (bitwise == BLAS's
// fma(w, s, acc) with s in {0,1}; validated r12)
__device__ __forceinline__ void fma25(float w, const float* __restrict__ rec,
                                      float* __restrict__ acc) {
    #pragma unroll
    for (int t = 0; t < TS; ++t) acc[t] = fmaf(w, rec[t], acc[t]);
}

// ---------------- K1: fused, ONE batch row per block (2048 blocks) ----------------
__global__ __launch_bounds__(256, 5) void k1_fused(
    const float* __restrict__ obs, const float* __restrict__ emean, const float* __restrict__ estd,
    const float* __restrict__ w1t, const float* __restrict__ w2t, const float* __restrict__ w3t,
    const float* __restrict__ b1, const float* __restrict__ b2, const float* __restrict__ b3,
    const float* __restrict__ dw, const float* __restrict__ db, float* __restrict__ out)
{
    __shared__ __align__(16) float pairL[256 * RECF];  // 28,672 B row records
    __shared__ __align__(16) int   idxL[256];          //  1,024 B premult indices
    __shared__ uint32_t waveCnt[4];
    __shared__ float cnt3[OUTP];

    const int tid = threadIdx.x;
    const int wave = tid >> 6, lane = tid & 63;
    const int b = blockIdx.x;
    const unsigned long long below = (1ull << lane) - 1ull;

    // ---- Phase A: population encoding, numpy-faithful fp32 op-by-op ----
    uint32_t msk[10];
    #pragma unroll
    for (int k = 0; k < 10; ++k) {
        int i = k * 256 + tid;
        int o = i / 10;
        float x  = obs[b * OBSD + o];
        float mu = emean[i];
        float sd = estd[i];
        float d  = __fadd_rn(x, -mu);
        float d2 = __fmul_rn(d, d);
        float nm = __fmul_rn(-0.5f, d2);
        float dn = __fmul_rn(sd, sd);
        float a  = exp_cr(__fdiv_rn(nm, dn));
        float volt = 0.0f;
        uint32_t m = 0;
        #pragma unroll
        for (int t = 0; t < TS; ++t) {
            volt = __fadd_rn(volt, a);
            if (volt > 0.999f) { m |= (1u << t); volt = __fadd_rn(volt, -0.999f); }
        }
        msk[k] = m;
    }

    // ---- Phase B: event GEMM1 in two halves (<=256 active rows per half).
    // K-blocks {320 x 8} left-assoc via sorted-index boundary folds (r8-valid). ----
    float acc[TS], part[TS];
    #pragma unroll
    for (int t = 0; t < TS; ++t) { acc[t] = 0.0f; part[t] = 0.0f; }
    int nextB = 320 * H;

    for (int h = 0; h < 2; ++h) {
        // build compacted records (ascending i) for this half
        int runTot = 0;
        for (int kk = 0; kk < 5; ++kk) {
            int k = h * 5 + kk;
            uint32_t m = msk[k];
            unsigned long long bal = __ballot(m != 0u);
            if (lane == 0) waveCnt[wave] = (uint32_t)__popcll(bal);
            __syncthreads();
            int base = runTot, tot = 0;
            #pragma unroll
            for (int w = 0; w < 4; ++w) {
                if (w < wave) base += (int)waveCnt[w];
                tot += (int)waveCnt[w];
            }
            if (m) {
                int pos = base + (int)__popcll(bal & below);
                idxL[pos] = (k * 256 + tid) * H;
                write_rec(pairL, pos, m);
            }
            runTot += tot;
            __syncthreads();
        }
        const int nAct = runTot;

        // walk with STATIC 4-deep prefetch (register-resident); fma25 per row
        int pi0 = 0, pi1 = 0, pi2 = 0, pi3 = 0;
        float pw0 = 0, pw1 = 0, pw2 = 0, pw3 = 0;
        if (nAct > 0) { pi0 = rfl(idxL[0]); pw0 = w1t[pi0 + tid]; }
        if (nAct > 1) { pi1 = rfl(idxL[1]); pw1 = w1t[pi1 + tid]; }
        if (nAct > 2) { pi2 = rfl(idxL[2]); pw2 = w1t[pi2 + tid]; }
        if (nAct > 3) { pi3 = rfl(idxL[3]); pw3 = w1t[pi3 + tid]; }
        int j = 0;
        for (; j + 4 <= nAct; j += 4) {
            int ci0 = pi0, ci1 = pi1, ci2 = pi2, ci3 = pi3;
            float cw0 = pw0, cw1 = pw1, cw2 = pw2, cw3 = pw3;
            if (j + 4 < nAct) { pi0 = rfl(idxL[j + 4]); pw0 = w1t[pi0 + tid]; }
            if (j + 5 < nAct) { pi1 = rfl(idxL[j + 5]); pw1 = w1t[pi1 + tid]; }
            if (j + 6 < nAct) { pi2 = rfl(idxL[j + 6]); pw2 = w1t[pi2 + tid]; }
            if (j + 7 < nAct) { pi3 = rfl(idxL[j + 7]); pw3 = w1t[pi3 + tid]; }
            while (ci0 >= nextB) {
                #pragma unroll
                for (int t = 0; t < TS; ++t) { acc[t] = __fadd_rn(acc[t], part[t]); part[t] = 0.0f; }
                nextB += 320 * H;
            }
            fma25(cw0, &pairL[j * RECF], part);
            while (ci1 >= nextB) {
                #pragma unroll
                for (int t = 0; t < TS; ++t) { acc[t] = __fadd_rn(acc[t], part[t]); part[t] = 0.0f; }
                nextB += 320 * H;
            }
            fma25(cw1, &pairL[(j + 1) * RECF], part);
            while (ci2 >= nextB) {
                #pragma unroll
                for (int t = 0; t < TS; ++t) { acc[t] = __fadd_rn(acc[t], part[t]); part[t] = 0.0f; }
                nextB += 320 * H;
            }
            fma25(cw2, &pairL[(j + 2) * RECF], part);
            while (ci3 >= nextB) {
                #pragma unroll
                for (int t = 0; t < TS; ++t) { acc[t] = __fadd_rn(acc[t], part[t]); part[t] = 0.0f; }
                nextB += 320 * H;
            }
            fma25(cw3, &pairL[(j + 3) * RECF], part);
        }
        for (; j < nAct; ++j) {           // remainder (<=3 rows)
            int ii = rfl(idxL[j]);
            float wv = w1t[ii + tid];
            while (ii >= nextB) {
                #pragma unroll
                for (int t = 0; t < TS; ++t) { acc[t] = __fadd_rn(acc[t], part[t]); part[t] = 0.0f; }
                nextB += 320 * H;
            }
            fma25(wv, &pairL[j * RECF], part);
        }
        __syncthreads();   // records dead; next half (or C1 build) may overwrite
    }
    // final fold (remaining partial; empty trailing blocks are exact no-ops)
    #pragma unroll
    for (int t = 0; t < TS; ++t) acc[t] = __fadd_rn(acc[t], part[t]);

    // ---- C1: layer-1 LIF, all 25 steps; build layer-1 spike records ----
    uint32_t m1 = 0;
    {
        const float b1v = b1[tid];
        float c1 = 0, v1 = 0, s1 = 0;
        #pragma unroll
        for (int t = 0; t < TS; ++t) {
            lif_step(acc[t], b1v, c1, v1, s1);
            if (s1 != 0.0f) m1 |= (1u << t);
        }
    }
    unsigned long long bal = __ballot(m1 != 0u);
    if (lane == 0) waveCnt[wave] = (uint32_t)__popcll(bal);
    __syncthreads();
    int base1 = 0, n1 = 0;
    #pragma unroll
    for (int w = 0; w < 4; ++w) {
        if (w < wave) base1 += (int)waveCnt[w];
        n1 += (int)waveCnt[w];
    }
    if (m1) {
        int pos = base1 + (int)__popcll(bal & below);
        idxL[pos] = tid * H;
        write_rec(pairL, pos, m1);
    }
    __syncthreads();

    // ---- C2: batched GEMM2 walk (K=256, single block) + layer-2 LIF ----
    float acc2[TS];
    #pragma unroll
    for (int t = 0; t < TS; ++t) acc2[t] = 0.0f;
    {
        int pi0 = 0, pi1 = 0, pi2 = 0, pi3 = 0;
        float pw0 = 0, pw1 = 0, pw2 = 0, pw3 = 0;
        if (n1 > 0) { pi0 = rfl(idxL[0]); pw0 = w2t[pi0 + tid]; }
        if (n1 > 1) { pi1 = rfl(idxL[1]); pw1 = w2t[pi1 + tid]; }
        if (n1 > 2) { pi2 = rfl(idxL[2]); pw2 = w2t[pi2 + tid]; }
        if (n1 > 3) { pi3 = rfl(idxL[3]); pw3 = w2t[pi3 + tid]; }
        int j = 0;
        for (; j + 4 <= n1; j += 4) {
            float cw0 = pw0, cw1 = pw1, cw2 = pw2, cw3 = pw3;
            if (j + 4 < n1) { pi0 = rfl(idxL[j + 4]); pw0 = w2t[pi0 + tid]; }
            if (j + 5 < n1) { pi1 = rfl(idxL[j + 5]); pw1 = w2t[pi1 + tid]; }
            if (j + 6 < n1) { pi2 = rfl(idxL[j + 6]); pw2 = w2t[pi2 + tid]; }
            if (j + 7 < n1) { pi3 = rfl(idxL[j + 7]); pw3 = w2t[pi3 + tid]; }
            fma25(cw0, &pairL[j * RECF], acc2);
            fma25(cw1, &pairL[(j + 1) * RECF], acc2);
            fma25(cw2, &pairL[(j + 2) * RECF], acc2);
            fma25(cw3, &pairL[(j + 3) * RECF], acc2);
        }
        for (; j < n1; ++j) {
            int ii = rfl(idxL[j]);
            fma25(w2t[ii + tid], &pairL[j * RECF], acc2);
        }
    }
    uint32_t m2 = 0;
    {
        const float b2v = b2[tid];
        float c2 = 0, v2 = 0, s2 = 0;
        #pragma unroll
        for (int t = 0; t < TS; ++t) {
            lif_step(acc2[t], b2v, c2, v2, s2);
            if (s2 != 0.0f) m2 |= (1u << t);
        }
    }
    __syncthreads();   // C2 walk reads done before list-2 build overwrites
    bal = __ballot(m2 != 0u);
    if (lane == 0) waveCnt[wave] = (uint32_t)__popcll(bal);
    __syncthreads();
    int base2 = 0, n2 = 0;
    #pragma unroll
    for (int w = 0; w < 4; ++w) {
        if (w < wave) base2 += (int)waveCnt[w];
        n2 += (int)waveCnt[w];
    }
    if (m2) {
        int pos = base2 + (int)__popcll(bal & below);
        idxL[pos] = tid * OUTP;
        write_rec(pairL, pos, m2);
    }
    __syncthreads();

    // ---- C3: batched GEMM3 walk + layer-3 LIF (threads 0..79) ----
    if (tid < OUTP) {
        float x3[TS];
        #pragma unroll
        for (int t = 0; t < TS; ++t) x3[t] = 0.0f;
        int pi0 = 0, pi1 = 0, pi2 = 0, pi3 = 0;
        float pw0 = 0, pw1 = 0, pw2 = 0, pw3 = 0;
        if (n2 > 0) { pi0 = rfl(idxL[0]); pw0 = w3t[pi0 + tid]; }
        if (n2 > 1) { pi1 = rfl(idxL[1]); pw1 = w3t[pi1 + tid]; }
        if (n2 > 2) { pi2 = rfl(idxL[2]); pw2 = w3t[pi2 + tid]; }
        if (n2 > 3) { pi3 = rfl(idxL[3]); pw3 = w3t[pi3 + tid]; }
        int j = 0;
        for (; j + 4 <= n2; j += 4) {
            float cw0 = pw0, cw1 = pw1, cw2 = pw2, cw3 = pw3;
            if (j + 4 < n2) { pi0 = rfl(idxL[j + 4]); pw0 = w3t[pi0 + tid]; }
            if (j + 5 < n2) { pi1 = rfl(idxL[j + 5]); pw1 = w3t[pi1 + tid]; }
            if (j + 6 < n2) { pi2 = rfl(idxL[j + 6]); pw2 = w3t[pi2 + tid]; }
            if (j + 7 < n2) { pi3 = rfl(idxL[j + 7]); pw3 = w3t[pi3 + tid]; }
            fma25(cw0, &pairL[j * RECF], x3);
            fma25(cw1, &pairL[(j + 1) * RECF], x3);
            fma25(cw2, &pairL[(j + 2) * RECF], x3);
            fma25(cw3, &pairL[(j + 3) * RECF], x3);
        }
        for (; j < n2; ++j) {
            int ii = rfl(idxL[j]);
            fma25(w3t[ii + tid], &pairL[j * RECF], x3);
        }
        const float b3v = b3[tid];
        float c3 = 0, v3 = 0, s3 = 0, ct = 0;
        #pragma unroll
        for (int t = 0; t < TS; ++t) {
            lif_step(x3[t], b3v, c3, v3, s3);
            ct += s3;
        }
        cnt3[tid] = ct;
    }
    __syncthreads();

    // ---- decode: per-op rounding like np einsum (no FMA) ----
    if (tid < 8) {
        float raw = 0.0f;
        #pragma unroll
        for (int pp = 0; pp < POP; ++pp) {
            float po = __fdiv_rn(cnt3[tid * POP + pp], 25.0f);
            raw = __fadd_rn(raw, __fmul_rn(po, dw[tid * POP + pp]));
        }
        raw = __fadd_rn(raw, db[tid]);
        out[b * 8 + tid] = (float)tanh((double)raw);
    }
}

extern "C" void kernel_launch(void* const* d_in, const int* in_sizes, int n_in,
                              void* d_out, int out_size, void* d_ws, size_t ws_size,
                              hipStream_t stream) {
    const float* obs   = (const float*)d_in[0];
    const float* emean = (const float*)d_in[1];
    const float* estd  = (const float*)d_in[2];
    const float* w1    = (const float*)d_in[3];
    const float* b1    = (const float*)d_in[4];
    const float* w2    = (const float*)d_in[5];
    const float* b2    = (const float*)d_in[6];
    const float* w3    = (const float*)d_in[7];
    const float* b3    = (const float*)d_in[8];
    const float* dw    = (const float*)d_in[9];
    const float* db    = (const float*)d_in[10];
    float* out = (float*)d_out;

    char* ws = (char*)d_ws;
    float* w1t = (float*)(ws);                 // 655360 * 4 = 2,621,440 B
    float* w2t = (float*)(ws + 2621440);       //  65536 * 4 =   262,144 B
    float* w3t = (float*)(ws + 2883584);       //  20480 * 4 =    81,920 B

    k0_transpose<<<2896, 256, 0, stream>>>(w1, w2, w3, w1t, w2t, w3t);
    k1_fused<<<NB, 256, 0, stream>>>(obs, emean, estd, w1t, w2t, w3t,
                                     b1, b2, b3, dw, db, out);
}

// Round 16
// 417.620 us; speedup vs baseline: 1.6911x; 1.3103x over previous
//
#include <hip/hip_runtime.h>
#include <stdint.h>

#define NB 2048
#define OBSD 256
#define POP 10
#define NIN 2560       // OBS_DIM * POP_DIM
#define H 256          // HID1 == HID2
#define OUTP 80        // ACT_DIM * DE_POP
#define TS 25
#define RECF 28        // floats per row record (25 bit-floats + 3 pad, 112 B)

typedef __attribute__((ext_vector_type(2))) float f2;

// correctly-rounded fp32 exp (fp64 exp then round) — matches SVML high-accuracy
// expf that numpy dispatches to on AVX512 hosts (validated r8: absmax 4.8e-7).
__device__ __forceinline__ float exp_cr(float x) {
    return (float)exp((double)x);
}

__device__ __forceinline__ int rfl(int v) {
    return __builtin_amdgcn_readfirstlane(v);
}

// 25-float accumulator as 12 float2 pairs + 1 scalar (v_pk_fma_f32 path)
struct Acc25 {
    f2 p[12];
    float last;
};

__device__ __forceinline__ void acc_zero(Acc25& a) {
    #pragma unroll
    for (int i = 0; i < 12; ++i) { a.p[i].x = 0.0f; a.p[i].y = 0.0f; }
    a.last = 0.0f;
}

// fold part into acc (per-element RN add == r12's scalar folds), zero part
__device__ __forceinline__ void acc_fold(Acc25& acc, Acc25& part) {
    #pragma unroll
    for (int i = 0; i < 12; ++i) {
        acc.p[i].x = __fadd_rn(acc.p[i].x, part.p[i].x);
        acc.p[i].y = __fadd_rn(acc.p[i].y, part.p[i].y);
        part.p[i].x = 0.0f; part.p[i].y = 0.0f;
    }
    acc.last = __fadd_rn(acc.last, part.last);
    part.last = 0.0f;
}

__device__ __forceinline__ void acc_unpack(const Acc25& a, float* __restrict__ t) {
    #pragma unroll
    for (int i = 0; i < 12; ++i) { t[2 * i] = a.p[i].x; t[2 * i + 1] = a.p[i].y; }
    t[24] = a.last;
}

// 25-term fma chain: acc[t] = fma(w, bit[t], acc[t]). v_pk_fma_f32 does two
// independent IEEE-RN fp32 fmas per inst -> per-element bitwise == scalar fmaf
// == BLAS fma(w, s, acc) with s in {0,1} (validated r12).
__device__ __forceinline__ void fma25(float w, const float* __restrict__ rec, Acc25& a) {
    f2 wp; wp.x = w; wp.y = w;
    #pragma unroll
    for (int i = 0; i < 12; ++i) {
        f2 r = *(const f2*)&rec[2 * i];
#if __has_builtin(__builtin_elementwise_fma)
        a.p[i] = __builtin_elementwise_fma(wp, r, a.p[i]);
#else
        a.p[i].x = fmaf(w, r.x, a.p[i].x);
        a.p[i].y = fmaf(w, r.y, a.p[i].y);
#endif
    }
    a.last = fmaf(w, rec[24], a.last);
}

// ---------------- K0: transpose weights into fp32 [k][n] layouts in ws ----------------
__global__ __launch_bounds__(256) void k0_transpose(
    const float* __restrict__ w1, const float* __restrict__ w2, const float* __restrict__ w3,
    float* __restrict__ w1t, float* __restrict__ w2t, float* __restrict__ w3t)
{
    int idx = blockIdx.x * 256 + threadIdx.x;
    const int N1 = NIN * H;       // 655360
    const int N2 = H * H;         // 65536
    const int N3 = H * OUTP;      // 20480
    if (idx < N1) {
        int i = idx >> 8, j = idx & 255;
        w1t[idx] = w1[j * NIN + i];
    } else if (idx < N1 + N2) {
        int k = idx - N1;
        int i = k >> 8, j = k & 255;
        w2t[k] = w2[j * H + i];
    } else if (idx < N1 + N2 + N3) {
        int k = idx - N1 - N2;
        int i = k / OUTP, j = k - i * OUTP;
        w3t[k] = w3[j * H + i];
    }
}

// One LIF step, numpy-faithful per-op rounding (no contraction):
__device__ __forceinline__ void lif_step(float x, float bv, float& c, float& v, float& s) {
    float cn = __fadd_rn(__fadd_rn(__fmul_rn(c, 0.5f), x), bv);
    c = cn;
    float vp = v;
    float t  = __fmul_rn(__fmul_rn(vp, 0.75f), __fadd_rn(1.0f, -s));
    float vn = __fadd_rn(t, cn);
    float ag = __fdiv_rn(__fadd_rn(vp, -vn), 3.0f);
    float ex = exp_cr(ag);
    float vth = __fadd_rn(0.25f, __fmul_rn(0.5f, __fadd_rn(ex, -1.0f)));
    v = vn;
    s = (vn > vth) ? 1.0f : 0.0f;
}

// write one row record: 25 spike bits as floats {0.0,1.0} + 3 pad (7 float4s)
__device__ __forceinline__ void write_rec(float* __restrict__ pairL, int pos, uint32_t m) {
    float f[RECF];
    #pragma unroll
    for (int t = 0; t < TS; ++t) f[t] = (m >> t) & 1u ? 1.0f : 0.0f;
    f[25] = 0.0f; f[26] = 0.0f; f[27] = 0.0f;
    float4* dst = (float4*)&pairL[pos * RECF];
    #pragma unroll
    for (int p = 0; p < 7; ++p)
        dst[p] = make_float4(f[4 * p], f[4 * p + 1], f[4 * p + 2], f[4 * p + 3]);
}

// ---------------- K1: fused, ONE batch row per block (2048 blocks) ----------------
__global__ __launch_bounds__(256, 4) void k1_fused(
    const float* __restrict__ obs, const float* __restrict__ emean, const float* __restrict__ estd,
    const float* __restrict__ w1t, const float* __restrict__ w2t, const float* __restrict__ w3t,
    const float* __restrict__ b1, const float* __restrict__ b2, const float* __restrict__ b3,
    const float* __restrict__ dw, const float* __restrict__ db, float* __restrict__ out)
{
    __shared__ __align__(16) float pairL[256 * RECF];  // 28,672 B row records
    __shared__ __align__(16) int   idxL[256];          //  1,024 B premult indices
    __shared__ uint32_t waveCnt[4];
    __shared__ float cnt3[OUTP];

    const int tid = threadIdx.x;
    const int wave = tid >> 6, lane = tid & 63;
    const int b = blockIdx.x;
    const unsigned long long below = (1ull << lane) - 1ull;

    // ---- Phase A: population encoding, numpy-faithful fp32 op-by-op ----
    uint32_t msk[10];
    #pragma unroll
    for (int k = 0; k < 10; ++k) {
        int i = k * 256 + tid;
        int o = i / 10;
        float x  = obs[b * OBSD + o];
        float mu = emean[i];
        float sd = estd[i];
        float d  = __fadd_rn(x, -mu);
        float d2 = __fmul_rn(d, d);
        float nm = __fmul_rn(-0.5f, d2);
        float dn = __fmul_rn(sd, sd);
        float a  = exp_cr(__fdiv_rn(nm, dn));
        float volt = 0.0f;
        uint32_t m = 0;
        #pragma unroll
        for (int t = 0; t < TS; ++t) {
            volt = __fadd_rn(volt, a);
            if (volt > 0.999f) { m |= (1u << t); volt = __fadd_rn(volt, -0.999f); }
        }
        msk[k] = m;
    }

    // ---- Phase B: event GEMM1 in two halves (<=256 active rows per half).
    // K-blocks {320 x 8} left-assoc via sorted-index boundary folds (r8-valid). ----
    Acc25 acc, part;
    acc_zero(acc); acc_zero(part);
    int nextB = 320 * H;

    for (int h = 0; h < 2; ++h) {
        // build compacted records (ascending i) for this half
        int runTot = 0;
        for (int kk = 0; kk < 5; ++kk) {
            int k = h * 5 + kk;
            uint32_t m = msk[k];
            unsigned long long bal = __ballot(m != 0u);
            if (lane == 0) waveCnt[wave] = (uint32_t)__popcll(bal);
            __syncthreads();
            int base = runTot, tot = 0;
            #pragma unroll
            for (int w = 0; w < 4; ++w) {
                if (w < wave) base += (int)waveCnt[w];
                tot += (int)waveCnt[w];
            }
            if (m) {
                int pos = base + (int)__popcll(bal & below);
                idxL[pos] = (k * 256 + tid) * H;
                write_rec(pairL, pos, m);
            }
            runTot += tot;
            __syncthreads();
        }
        const int nAct = runTot;

        // walk with STATIC 4-deep prefetch (register-resident); fma25 per row
        int pi0 = 0, pi1 = 0, pi2 = 0, pi3 = 0;
        float pw0 = 0, pw1 = 0, pw2 = 0, pw3 = 0;
        if (nAct > 0) { pi0 = rfl(idxL[0]); pw0 = w1t[pi0 + tid]; }
        if (nAct > 1) { pi1 = rfl(idxL[1]); pw1 = w1t[pi1 + tid]; }
        if (nAct > 2) { pi2 = rfl(idxL[2]); pw2 = w1t[pi2 + tid]; }
        if (nAct > 3) { pi3 = rfl(idxL[3]); pw3 = w1t[pi3 + tid]; }
        int j = 0;
        for (; j + 4 <= nAct; j += 4) {
            int ci0 = pi0, ci1 = pi1, ci2 = pi2, ci3 = pi3;
            float cw0 = pw0, cw1 = pw1, cw2 = pw2, cw3 = pw3;
            if (j + 4 < nAct) { pi0 = rfl(idxL[j + 4]); pw0 = w1t[pi0 + tid]; }
            if (j + 5 < nAct) { pi1 = rfl(idxL[j + 5]); pw1 = w1t[pi1 + tid]; }
            if (j + 6 < nAct) { pi2 = rfl(idxL[j + 6]); pw2 = w1t[pi2 + tid]; }
            if (j + 7 < nAct) { pi3 = rfl(idxL[j + 7]); pw3 = w1t[pi3 + tid]; }
            while (ci0 >= nextB) { acc_fold(acc, part); nextB += 320 * H; }
            fma25(cw0, &pairL[j * RECF], part);
            while (ci1 >= nextB) { acc_fold(acc, part); nextB += 320 * H; }
            fma25(cw1, &pairL[(j + 1) * RECF], part);
            while (ci2 >= nextB) { acc_fold(acc, part); nextB += 320 * H; }
            fma25(cw2, &pairL[(j + 2) * RECF], part);
            while (ci3 >= nextB) { acc_fold(acc, part); nextB += 320 * H; }
            fma25(cw3, &pairL[(j + 3) * RECF], part);
        }
        for (; j < nAct; ++j) {           // remainder (<=3 rows)
            int ii = rfl(idxL[j]);
            float wv = w1t[ii + tid];
            while (ii >= nextB) { acc_fold(acc, part); nextB += 320 * H; }
            fma25(wv, &pairL[j * RECF], part);
        }
        __syncthreads();   // records dead; next half (or C1 build) may overwrite
    }
    // final fold (remaining partial; empty trailing blocks are exact no-ops)
    acc_fold(acc, part);

    // ---- C1: layer-1 LIF, all 25 steps; build layer-1 spike records ----
    uint32_t m1 = 0;
    {
        float cur[TS];
        acc_unpack(acc, cur);
        const float b1v = b1[tid];
        float c1 = 0, v1 = 0, s1 = 0;
        #pragma unroll
        for (int t = 0; t < TS; ++t) {
            lif_step(cur[t], b1v, c1, v1, s1);
            if (s1 != 0.0f) m1 |= (1u << t);
        }
    }
    unsigned long long bal = __ballot(m1 != 0u);
    if (lane == 0) waveCnt[wave] = (uint32_t)__popcll(bal);
    __syncthreads();
    int base1 = 0, n1 = 0;
    #pragma unroll
    for (int w = 0; w < 4; ++w) {
        if (w < wave) base1 += (int)waveCnt[w];
        n1 += (int)waveCnt[w];
    }
    if (m1) {
        int pos = base1 + (int)__popcll(bal & below);
        idxL[pos] = tid * H;
        write_rec(pairL, pos, m1);
    }
    __syncthreads();

    // ---- C2: batched GEMM2 walk (K=256, single block) + layer-2 LIF ----
    Acc25 acc2;
    acc_zero(acc2);
    {
        int pi0 = 0, pi1 = 0, pi2 = 0, pi3 = 0;
        float pw0 = 0, pw1 = 0, pw2 = 0, pw3 = 0;
        if (n1 > 0) { pi0 = rfl(idxL[0]); pw0 = w2t[pi0 + tid]; }
        if (n1 > 1) { pi1 = rfl(idxL[1]); pw1 = w2t[pi1 + tid]; }
        if (n1 > 2) { pi2 = rfl(idxL[2]); pw2 = w2t[pi2 + tid]; }
        if (n1 > 3) { pi3 = rfl(idxL[3]); pw3 = w2t[pi3 + tid]; }
        int j = 0;
        for (; j + 4 <= n1; j += 4) {
            float cw0 = pw0, cw1 = pw1, cw2 = pw2, cw3 = pw3;
            if (j + 4 < n1) { pi0 = rfl(idxL[j + 4]); pw0 = w2t[pi0 + tid]; }
            if (j + 5 < n1) { pi1 = rfl(idxL[j + 5]); pw1 = w2t[pi1 + tid]; }
            if (j + 6 < n1) { pi2 = rfl(idxL[j + 6]); pw2 = w2t[pi2 + tid]; }
            if (j + 7 < n1) { pi3 = rfl(idxL[j + 7]); pw3 = w2t[pi3 + tid]; }
            fma25(cw0, &pairL[j * RECF], acc2);
            fma25(cw1, &pairL[(j + 1) * RECF], acc2);
            fma25(cw2, &pairL[(j + 2) * RECF], acc2);
            fma25(cw3, &pairL[(j + 3) * RECF], acc2);
        }
        for (; j < n1; ++j) {
            int ii = rfl(idxL[j]);
            fma25(w2t[ii + tid], &pairL[j * RECF], acc2);
        }
    }
    uint32_t m2 = 0;
    {
        float cur[TS];
        acc_unpack(acc2, cur);
        const float b2v = b2[tid];
        float c2 = 0, v2 = 0, s2 = 0;
        #pragma unroll
        for (int t = 0; t < TS; ++t) {
            lif_step(cur[t], b2v, c2, v2, s2);
            if (s2 != 0.0f) m2 |= (1u << t);
        }
    }
    __syncthreads();   // C2 walk reads done before list-2 build overwrites
    bal = __ballot(m2 != 0u);
    if (lane == 0) waveCnt[wave] = (uint32_t)__popcll(bal);
    __syncthreads();
    int base2 = 0, n2 = 0;
    #pragma unroll
    for (int w = 0; w < 4; ++w) {
        if (w < wave) base2 += (int)waveCnt[w];
        n2 += (int)waveCnt[w];
    }
    if (m2) {
        int pos = base2 + (int)__popcll(bal & below);
        idxL[pos] = tid * OUTP;
        write_rec(pairL, pos, m2);
    }
    __syncthreads();

    // ---- C3: batched GEMM3 walk + layer-3 LIF (threads 0..79) ----
    if (tid < OUTP) {
        Acc25 x3;
        acc_zero(x3);
        int pi0 = 0, pi1 = 0, pi2 = 0, pi3 = 0;
        float pw0 = 0, pw1 = 0, pw2 = 0, pw3 = 0;
        if (n2 > 0) { pi0 = rfl(idxL[0]); pw0 = w3t[pi0 + tid]; }
        if (n2 > 1) { pi1 = rfl(idxL[1]); pw1 = w3t[pi1 + tid]; }
        if (n2 > 2) { pi2 = rfl(idxL[2]); pw2 = w3t[pi2 + tid]; }
        if (n2 > 3) { pi3 = rfl(idxL[3]); pw3 = w3t[pi3 + tid]; }
        int j = 0;
        for (; j + 4 <= n2; j += 4) {
            float cw0 = pw0, cw1 = pw1, cw2 = pw2, cw3 = pw3;
            if (j + 4 < n2) { pi0 = rfl(idxL[j + 4]); pw0 = w3t[pi0 + tid]; }
            if (j + 5 < n2) { pi1 = rfl(idxL[j + 5]); pw1 = w3t[pi1 + tid]; }
            if (j + 6 < n2) { pi2 = rfl(idxL[j + 6]); pw2 = w3t[pi2 + tid]; }
            if (j + 7 < n2) { pi3 = rfl(idxL[j + 7]); pw3 = w3t[pi3 + tid]; }
            fma25(cw0, &pairL[j * RECF], x3);
            fma25(cw1, &pairL[(j + 1) * RECF], x3);
            fma25(cw2, &pairL[(j + 2) * RECF], x3);
            fma25(cw3, &pairL[(j + 3) * RECF], x3);
        }
        for (; j < n2; ++j) {
            int ii = rfl(idxL[j]);
            fma25(w3t[ii + tid], &pairL[j * RECF], x3);
        }
        float cur[TS];
        acc_unpack(x3, cur);
        const float b3v = b3[tid];
        float c3 = 0, v3 = 0, s3 = 0, ct = 0;
        #pragma unroll
        for (int t = 0; t < TS; ++t) {
            lif_step(cur[t], b3v, c3, v3, s3);
            ct += s3;
        }
        cnt3[tid] = ct;
    }
    __syncthreads();

    // ---- decode: per-op rounding like np einsum (no FMA) ----
    if (tid < 8) {
        float raw = 0.0f;
        #pragma unroll
        for (int pp = 0; pp < POP; ++pp) {
            float po = __fdiv_rn(cnt3[tid * POP + pp], 25.0f);
            raw = __fadd_rn(raw, __fmul_rn(po, dw[tid * POP + pp]));
        }
        raw = __fadd_rn(raw, db[tid]);
        out[b * 8 + tid] = (float)tanh((double)raw);
    }
}

extern "C" void kernel_launch(void* const* d_in, const int* in_sizes, int n_in,
                              void* d_out, int out_size, void* d_ws, size_t ws_size,
                              hipStream_t stream) {
    const float* obs   = (const float*)d_in[0];
    const float* emean = (const float*)d_in[1];
    const float* estd  = (const float*)d_in[2];
    const float* w1    = (const float*)d_in[3];
    const float* b1    = (const float*)d_in[4];
    const float* w2    = (const float*)d_in[5];
    const float* b2    = (const float*)d_in[6];
    const float* w3    = (const float*)d_in[7];
    const float* b3    = (const float*)d_in[8];
    const float* dw    = (const float*)d_in[9];
    const float* db    = (const float*)d_in[10];
    float* out = (float*)d_out;

    char* ws = (char*)d_ws;
    float* w1t = (float*)(ws);                 // 655360 * 4 = 2,621,440 B
    float* w2t = (float*)(ws + 2621440);       //  65536 * 4 =   262,144 B
    float* w3t = (float*)(ws + 2883584);       //  20480 * 4 =    81,920 B

    k0_transpose<<<2896, 256, 0, stream>>>(w1, w2, w3, w1t, w2t, w3t);
    k1_fused<<<NB, 256, 0, stream>>>(obs, emean, estd, w1t, w2t, w3t,
                                     b1, b2, b3, dw, db, out);
}

// Round 17
// 386.783 us; speedup vs baseline: 1.8260x; 1.0797x over previous
//
#include <hip/hip_runtime.h>
#include <stdint.h>

#define NB 2048
#define OBSD 256
#define POP 10
#define NIN 2560       // OBS_DIM * POP_DIM
#define H 256          // HID1 == HID2
#define OUTP 80        // ACT_DIM * DE_POP
#define TS 25
#define RECF 28        // floats per row record (25 bit-floats + 3 pad, 112 B)

typedef __attribute__((ext_vector_type(2))) float f2;

// correctly-rounded fp32 exp (fp64 exp then round) — matches SVML high-accuracy
// expf that numpy dispatches to on AVX512 hosts (validated r8: absmax 4.8e-7).
__device__ __forceinline__ float exp_cr(float x) {
    return (float)exp((double)x);
}

__device__ __forceinline__ int rfl(int v) {
    return __builtin_amdgcn_readfirstlane(v);
}

// 25-float accumulator as 12 float2 pairs + 1 scalar (v_pk_fma_f32 path)
struct Acc25 {
    f2 p[12];
    float last;
};

__device__ __forceinline__ void acc_zero(Acc25& a) {
    #pragma unroll
    for (int i = 0; i < 12; ++i) { a.p[i].x = 0.0f; a.p[i].y = 0.0f; }
    a.last = 0.0f;
}

// fold part into acc (per-element RN add == r12's scalar folds), zero part
__device__ __forceinline__ void acc_fold(Acc25& acc, Acc25& part) {
    #pragma unroll
    for (int i = 0; i < 12; ++i) {
        acc.p[i].x = __fadd_rn(acc.p[i].x, part.p[i].x);
        acc.p[i].y = __fadd_rn(acc.p[i].y, part.p[i].y);
        part.p[i].x = 0.0f; part.p[i].y = 0.0f;
    }
    acc.last = __fadd_rn(acc.last, part.last);
    part.last = 0.0f;
}

__device__ __forceinline__ void acc_unpack(const Acc25& a, float* __restrict__ t) {
    #pragma unroll
    for (int i = 0; i < 12; ++i) { t[2 * i] = a.p[i].x; t[2 * i + 1] = a.p[i].y; }
    t[24] = a.last;
}

// 25-term fma chain: acc[t] = fma(w, bit[t], acc[t]). v_pk_fma_f32 does two
// independent IEEE-RN fp32 fmas per inst -> per-element bitwise == scalar fmaf
// == BLAS fma(w, s, acc) with s in {0,1} (validated r12/r16). Records are read
// as 7 x ds_read_b128 (16B-aligned rows) to cut LDS instruction count.
__device__ __forceinline__ void fma25(float w, const float* __restrict__ rec, Acc25& a) {
    f2 wp; wp.x = w; wp.y = w;
    float4 q[7];
    #pragma unroll
    for (int i = 0; i < 7; ++i) q[i] = ((const float4*)rec)[i];
    const f2* r2 = (const f2*)q;   // 14 packed pairs in registers
    #pragma unroll
    for (int i = 0; i < 12; ++i) {
#if __has_builtin(__builtin_elementwise_fma)
        a.p[i] = __builtin_elementwise_fma(wp, r2[i], a.p[i]);
#else
        a.p[i].x = fmaf(w, r2[i].x, a.p[i].x);
        a.p[i].y = fmaf(w, r2[i].y, a.p[i].y);
#endif
    }
    a.last = fmaf(w, q[6].x, a.last);
}

// ---------------- K0: transpose weights into fp32 [k][n] layouts in ws ----------------
__global__ __launch_bounds__(256) void k0_transpose(
    const float* __restrict__ w1, const float* __restrict__ w2, const float* __restrict__ w3,
    float* __restrict__ w1t, float* __restrict__ w2t, float* __restrict__ w3t)
{
    int idx = blockIdx.x * 256 + threadIdx.x;
    const int N1 = NIN * H;       // 655360
    const int N2 = H * H;         // 65536
    const int N3 = H * OUTP;      // 20480
    if (idx < N1) {
        int i = idx >> 8, j = idx & 255;
        w1t[idx] = w1[j * NIN + i];
    } else if (idx < N1 + N2) {
        int k = idx - N1;
        int i = k >> 8, j = k & 255;
        w2t[k] = w2[j * H + i];
    } else if (idx < N1 + N2 + N3) {
        int k = idx - N1 - N2;
        int i = k / OUTP, j = k - i * OUTP;
        w3t[k] = w3[j * H + i];
    }
}

// One LIF step, numpy-faithful per-op rounding. vth feeds ONLY the comparison,
// so we decide the spike with a certified interval from fast fp32 exp (~3 ulp)
// + conservative margin, falling back to the exact exp_cr per-op path only
// when |v - vth_approx| <= delta (prob ~1e-5). Decisions provably identical.
__device__ __forceinline__ void lif_step(float x, float bv, float& c, float& v, float& s) {
    float cn = __fadd_rn(__fadd_rn(__fmul_rn(c, 0.5f), x), bv);
    c = cn;
    float vp = v;
    float t  = __fmul_rn(__fmul_rn(vp, 0.75f), __fadd_rn(1.0f, -s));
    float vn = __fadd_rn(t, cn);
    float ag = __fdiv_rn(__fadd_rn(vp, -vn), 3.0f);
    v = vn;
    float ex_a  = __expf(ag);                       // fast f32 exp (v_exp_f32)
    float vth_a = 0.25f + 0.5f * (ex_a - 1.0f);
    float delta = 1e-5f * (ex_a + fabsf(vth_a) + 1.0f);
    if (vn > vth_a + delta) {
        s = 1.0f;
    } else if (vn < vth_a - delta) {
        s = 0.0f;
    } else {                                        // exact fallback (rare)
        float ex  = exp_cr(ag);
        float vth = __fadd_rn(0.25f, __fmul_rn(0.5f, __fadd_rn(ex, -1.0f)));
        s = (vn > vth) ? 1.0f : 0.0f;
    }
}

// write one row record: 25 spike bits as floats {0.0,1.0} + 3 pad (7 float4s)
__device__ __forceinline__ void write_rec(float* __restrict__ pairL, int pos, uint32_t m) {
    float f[RECF];
    #pragma unroll
    for (int t = 0; t < TS; ++t) f[t] = (m >> t) & 1u ? 1.0f : 0.0f;
    f[25] = 0.0f; f[26] = 0.0f; f[27] = 0.0f;
    float4* dst = (float4*)&pairL[pos * RECF];
    #pragma unroll
    for (int p = 0; p < 7; ++p)
        dst[p] = make_float4(f[4 * p], f[4 * p + 1], f[4 * p + 2], f[4 * p + 3]);
}

// ---------------- K1: fused, ONE batch row per block (2048 blocks) ----------------
__global__ __launch_bounds__(256, 4) void k1_fused(
    const float* __restrict__ obs, const float* __restrict__ emean, const float* __restrict__ estd,
    const float* __restrict__ w1t, const float* __restrict__ w2t, const float* __restrict__ w3t,
    const float* __restrict__ b1, const float* __restrict__ b2, const float* __restrict__ b3,
    const float* __restrict__ dw, const float* __restrict__ db, float* __restrict__ out)
{
    __shared__ __align__(16) float pairL[256 * RECF];  // 28,672 B row records
    __shared__ __align__(16) int   idxL[256];          //  1,024 B premult indices
    __shared__ uint32_t waveCnt[4];
    __shared__ float cnt3[OUTP];

    const int tid = threadIdx.x;
    const int wave = tid >> 6, lane = tid & 63;
    const int b = blockIdx.x;
    const unsigned long long below = (1ull << lane) - 1ull;

    // ---- Phase A: population encoding, numpy-faithful fp32 op-by-op.
    // Monotonicity screen: arg < -3.23 => a < 0.0396 => 25a(1+eps) < 0.991
    // < 0.999 => mask provably 0 with NO exp call. Active (~11%) pay exp_cr. ----
    uint32_t msk[10];
    #pragma unroll
    for (int k = 0; k < 10; ++k) {
        int i = k * 256 + tid;
        int o = i / 10;
        float x  = obs[b * OBSD + o];
        float mu = emean[i];
        float sd = estd[i];
        float d  = __fadd_rn(x, -mu);
        float d2 = __fmul_rn(d, d);
        float nm = __fmul_rn(-0.5f, d2);
        float dn = __fmul_rn(sd, sd);
        float arg = __fdiv_rn(nm, dn);
        uint32_t m = 0;
        if (arg >= -3.23f) {
            float a  = exp_cr(arg);
            float volt = 0.0f;
            #pragma unroll
            for (int t = 0; t < TS; ++t) {
                volt = __fadd_rn(volt, a);
                if (volt > 0.999f) { m |= (1u << t); volt = __fadd_rn(volt, -0.999f); }
            }
        }
        msk[k] = m;
    }

    // ---- Phase B: event GEMM1 in two halves (<=256 active rows per half).
    // K-blocks {320 x 8} left-assoc via sorted-index boundary folds (r8-valid). ----
    Acc25 acc, part;
    acc_zero(acc); acc_zero(part);
    int nextB = 320 * H;

    for (int h = 0; h < 2; ++h) {
        // build compacted records (ascending i) for this half
        int runTot = 0;
        for (int kk = 0; kk < 5; ++kk) {
            int k = h * 5 + kk;
            uint32_t m = msk[k];
            unsigned long long bal = __ballot(m != 0u);
            if (lane == 0) waveCnt[wave] = (uint32_t)__popcll(bal);
            __syncthreads();
            int base = runTot, tot = 0;
            #pragma unroll
            for (int w = 0; w < 4; ++w) {
                if (w < wave) base += (int)waveCnt[w];
                tot += (int)waveCnt[w];
            }
            if (m) {
                int pos = base + (int)__popcll(bal & below);
                idxL[pos] = (k * 256 + tid) * H;
                write_rec(pairL, pos, m);
            }
            runTot += tot;
            __syncthreads();
        }
        const int nAct = runTot;

        // walk with STATIC 4-deep prefetch (register-resident); fma25 per row
        int pi0 = 0, pi1 = 0, pi2 = 0, pi3 = 0;
        float pw0 = 0, pw1 = 0, pw2 = 0, pw3 = 0;
        if (nAct > 0) { pi0 = rfl(idxL[0]); pw0 = w1t[pi0 + tid]; }
        if (nAct > 1) { pi1 = rfl(idxL[1]); pw1 = w1t[pi1 + tid]; }
        if (nAct > 2) { pi2 = rfl(idxL[2]); pw2 = w1t[pi2 + tid]; }
        if (nAct > 3) { pi3 = rfl(idxL[3]); pw3 = w1t[pi3 + tid]; }
        int j = 0;
        for (; j + 4 <= nAct; j += 4) {
            int ci0 = pi0, ci1 = pi1, ci2 = pi2, ci3 = pi3;
            float cw0 = pw0, cw1 = pw1, cw2 = pw2, cw3 = pw3;
            if (j + 4 < nAct) { pi0 = rfl(idxL[j + 4]); pw0 = w1t[pi0 + tid]; }
            if (j + 5 < nAct) { pi1 = rfl(idxL[j + 5]); pw1 = w1t[pi1 + tid]; }
            if (j + 6 < nAct) { pi2 = rfl(idxL[j + 6]); pw2 = w1t[pi2 + tid]; }
            if (j + 7 < nAct) { pi3 = rfl(idxL[j + 7]); pw3 = w1t[pi3 + tid]; }
            while (ci0 >= nextB) { acc_fold(acc, part); nextB += 320 * H; }
            fma25(cw0, &pairL[j * RECF], part);
            while (ci1 >= nextB) { acc_fold(acc, part); nextB += 320 * H; }
            fma25(cw1, &pairL[(j + 1) * RECF], part);
            while (ci2 >= nextB) { acc_fold(acc, part); nextB += 320 * H; }
            fma25(cw2, &pairL[(j + 2) * RECF], part);
            while (ci3 >= nextB) { acc_fold(acc, part); nextB += 320 * H; }
            fma25(cw3, &pairL[(j + 3) * RECF], part);
        }
        for (; j < nAct; ++j) {           // remainder (<=3 rows)
            int ii = rfl(idxL[j]);
            float wv = w1t[ii + tid];
            while (ii >= nextB) { acc_fold(acc, part); nextB += 320 * H; }
            fma25(wv, &pairL[j * RECF], part);
        }
        __syncthreads();   // records dead; next half (or C1 build) may overwrite
    }
    // final fold (remaining partial; empty trailing blocks are exact no-ops)
    acc_fold(acc, part);

    // ---- C1: layer-1 LIF, all 25 steps; build layer-1 spike records ----
    uint32_t m1 = 0;
    {
        float cur[TS];
        acc_unpack(acc, cur);
        const float b1v = b1[tid];
        float c1 = 0, v1 = 0, s1 = 0;
        #pragma unroll
        for (int t = 0; t < TS; ++t) {
            lif_step(cur[t], b1v, c1, v1, s1);
            if (s1 != 0.0f) m1 |= (1u << t);
        }
    }
    unsigned long long bal = __ballot(m1 != 0u);
    if (lane == 0) waveCnt[wave] = (uint32_t)__popcll(bal);
    __syncthreads();
    int base1 = 0, n1 = 0;
    #pragma unroll
    for (int w = 0; w < 4; ++w) {
        if (w < wave) base1 += (int)waveCnt[w];
        n1 += (int)waveCnt[w];
    }
    if (m1) {
        int pos = base1 + (int)__popcll(bal & below);
        idxL[pos] = tid * H;
        write_rec(pairL, pos, m1);
    }
    __syncthreads();

    // ---- C2: batched GEMM2 walk (K=256, single block) + layer-2 LIF ----
    Acc25 acc2;
    acc_zero(acc2);
    {
        int pi0 = 0, pi1 = 0, pi2 = 0, pi3 = 0;
        float pw0 = 0, pw1 = 0, pw2 = 0, pw3 = 0;
        if (n1 > 0) { pi0 = rfl(idxL[0]); pw0 = w2t[pi0 + tid]; }
        if (n1 > 1) { pi1 = rfl(idxL[1]); pw1 = w2t[pi1 + tid]; }
        if (n1 > 2) { pi2 = rfl(idxL[2]); pw2 = w2t[pi2 + tid]; }
        if (n1 > 3) { pi3 = rfl(idxL[3]); pw3 = w2t[pi3 + tid]; }
        int j = 0;
        for (; j + 4 <= n1; j += 4) {
            float cw0 = pw0, cw1 = pw1, cw2 = pw2, cw3 = pw3;
            if (j + 4 < n1) { pi0 = rfl(idxL[j + 4]); pw0 = w2t[pi0 + tid]; }
            if (j + 5 < n1) { pi1 = rfl(idxL[j + 5]); pw1 = w2t[pi1 + tid]; }
            if (j + 6 < n1) { pi2 = rfl(idxL[j + 6]); pw2 = w2t[pi2 + tid]; }
            if (j + 7 < n1) { pi3 = rfl(idxL[j + 7]); pw3 = w2t[pi3 + tid]; }
            fma25(cw0, &pairL[j * RECF], acc2);
            fma25(cw1, &pairL[(j + 1) * RECF], acc2);
            fma25(cw2, &pairL[(j + 2) * RECF], acc2);
            fma25(cw3, &pairL[(j + 3) * RECF], acc2);
        }
        for (; j < n1; ++j) {
            int ii = rfl(idxL[j]);
            fma25(w2t[ii + tid], &pairL[j * RECF], acc2);
        }
    }
    uint32_t m2 = 0;
    {
        float cur[TS];
        acc_unpack(acc2, cur);
        const float b2v = b2[tid];
        float c2 = 0, v2 = 0, s2 = 0;
        #pragma unroll
        for (int t = 0; t < TS; ++t) {
            lif_step(cur[t], b2v, c2, v2, s2);
            if (s2 != 0.0f) m2 |= (1u << t);
        }
    }
    __syncthreads();   // C2 walk reads done before list-2 build overwrites
    bal = __ballot(m2 != 0u);
    if (lane == 0) waveCnt[wave] = (uint32_t)__popcll(bal);
    __syncthreads();
    int base2 = 0, n2 = 0;
    #pragma unroll
    for (int w = 0; w < 4; ++w) {
        if (w < wave) base2 += (int)waveCnt[w];
        n2 += (int)waveCnt[w];
    }
    if (m2) {
        int pos = base2 + (int)__popcll(bal & below);
        idxL[pos] = tid * OUTP;
        write_rec(pairL, pos, m2);
    }
    __syncthreads();

    // ---- C3: batched GEMM3 walk + layer-3 LIF (threads 0..79) ----
    if (tid < OUTP) {
        Acc25 x3;
        acc_zero(x3);
        int pi0 = 0, pi1 = 0, pi2 = 0, pi3 = 0;
        float pw0 = 0, pw1 = 0, pw2 = 0, pw3 = 0;
        if (n2 > 0) { pi0 = rfl(idxL[0]); pw0 = w3t[pi0 + tid]; }
        if (n2 > 1) { pi1 = rfl(idxL[1]); pw1 = w3t[pi1 + tid]; }
        if (n2 > 2) { pi2 = rfl(idxL[2]); pw2 = w3t[pi2 + tid]; }
        if (n2 > 3) { pi3 = rfl(idxL[3]); pw3 = w3t[pi3 + tid]; }
        int j = 0;
        for (; j + 4 <= n2; j += 4) {
            float cw0 = pw0, cw1 = pw1, cw2 = pw2, cw3 = pw3;
            if (j + 4 < n2) { pi0 = rfl(idxL[j + 4]); pw0 = w3t[pi0 + tid]; }
            if (j + 5 < n2) { pi1 = rfl(idxL[j + 5]); pw1 = w3t[pi1 + tid]; }
            if (j + 6 < n2) { pi2 = rfl(idxL[j + 6]); pw2 = w3t[pi2 + tid]; }
            if (j + 7 < n2) { pi3 = rfl(idxL[j + 7]); pw3 = w3t[pi3 + tid]; }
            fma25(cw0, &pairL[j * RECF], x3);
            fma25(cw1, &pairL[(j + 1) * RECF], x3);
            fma25(cw2, &pairL[(j + 2) * RECF], x3);
            fma25(cw3, &pairL[(j + 3) * RECF], x3);
        }
        for (; j < n2; ++j) {
            int ii = rfl(idxL[j]);
            fma25(w3t[ii + tid], &pairL[j * RECF], x3);
        }
        float cur[TS];
        acc_unpack(x3, cur);
        const float b3v = b3[tid];
        float c3 = 0, v3 = 0, s3 = 0, ct = 0;
        #pragma unroll
        for (int t = 0; t < TS; ++t) {
            lif_step(cur[t], b3v, c3, v3, s3);
            ct += s3;
        }
        cnt3[tid] = ct;
    }
    __syncthreads();

    // ---- decode: per-op rounding like np einsum (no FMA) ----
    if (tid < 8) {
        float raw = 0.0f;
        #pragma unroll
        for (int pp = 0; pp < POP; ++pp) {
            float po = __fdiv_rn(cnt3[tid * POP + pp], 25.0f);
            raw = __fadd_rn(raw, __fmul_rn(po, dw[tid * POP + pp]));
        }
        raw = __fadd_rn(raw, db[tid]);
        out[b * 8 + tid] = (float)tanh((double)raw);
    }
}

extern "C" void kernel_launch(void* const* d_in, const int* in_sizes, int n_in,
                              void* d_out, int out_size, void* d_ws, size_t ws_size,
                              hipStream_t stream) {
    const float* obs   = (const float*)d_in[0];
    const float* emean = (const float*)d_in[1];
    const float* estd  = (const float*)d_in[2];
    const float* w1    = (const float*)d_in[3];
    const float* b1    = (const float*)d_in[4];
    const float* w2    = (const float*)d_in[5];
    const float* b2    = (const float*)d_in[6];
    const float* w3    = (const float*)d_in[7];
    const float* b3    = (const float*)d_in[8];
    const float* dw    = (const float*)d_in[9];
    const float* db    = (const float*)d_in[10];
    float* out = (float*)d_out;

    char* ws = (char*)d_ws;
    float* w1t = (float*)(ws);                 // 655360 * 4 = 2,621,440 B
    float* w2t = (float*)(ws + 2621440);       //  65536 * 4 =   262,144 B
    float* w3t = (float*)(ws + 2883584);       //  20480 * 4 =    81,920 B

    k0_transpose<<<2896, 256, 0, stream>>>(w1, w2, w3, w1t, w2t, w3t);
    k1_fused<<<NB, 256, 0, stream>>>(obs, emean, estd, w1t, w2t, w3t,
                                     b1, b2, b3, dw, db, out);
}

// Round 18
// 383.779 us; speedup vs baseline: 1.8403x; 1.0078x over previous
//
#include <hip/hip_runtime.h>
#include <stdint.h>

#define NB 2048
#define OBSD 256
#define POP 10
#define NIN 2560       // OBS_DIM * POP_DIM
#define H 256          // HID1 == HID2
#define OUTP 80        // ACT_DIM * DE_POP
#define TS 25
#define RECF 28        // floats per row record (25 bit-floats + 3 pad, 112 B)

typedef __attribute__((ext_vector_type(2))) float f2;

// correctly-rounded fp32 exp (fp64 exp then round) — matches SVML high-accuracy
// expf that numpy dispatches to on AVX512 hosts (validated r8: absmax 4.8e-7).
__device__ __forceinline__ float exp_cr(float x) {
    return (float)exp((double)x);
}

__device__ __forceinline__ int rfl(int v) {
    return __builtin_amdgcn_readfirstlane(v);
}

// 25-float accumulator as 12 float2 pairs + 1 scalar (v_pk_fma_f32 path)
struct Acc25 {
    f2 p[12];
    float last;
};

__device__ __forceinline__ void acc_zero(Acc25& a) {
    #pragma unroll
    for (int i = 0; i < 12; ++i) { a.p[i].x = 0.0f; a.p[i].y = 0.0f; }
    a.last = 0.0f;
}

// fold part into acc (per-element RN add == r12's scalar folds), zero part
__device__ __forceinline__ void acc_fold(Acc25& acc, Acc25& part) {
    #pragma unroll
    for (int i = 0; i < 12; ++i) {
        acc.p[i].x = __fadd_rn(acc.p[i].x, part.p[i].x);
        acc.p[i].y = __fadd_rn(acc.p[i].y, part.p[i].y);
        part.p[i].x = 0.0f; part.p[i].y = 0.0f;
    }
    acc.last = __fadd_rn(acc.last, part.last);
    part.last = 0.0f;
}

__device__ __forceinline__ void acc_unpack(const Acc25& a, float* __restrict__ t) {
    #pragma unroll
    for (int i = 0; i < 12; ++i) { t[2 * i] = a.p[i].x; t[2 * i + 1] = a.p[i].y; }
    t[24] = a.last;
}

// 25-term fma chain: acc[t] = fma(w, bit[t], acc[t]). v_pk_fma_f32 does two
// independent IEEE-RN fp32 fmas per inst -> per-element bitwise == scalar fmaf
// == BLAS fma(w, s, acc) with s in {0,1} (validated r12/r16/r17). Records read
// as 7 x ds_read_b128.
__device__ __forceinline__ void fma25(float w, const float* __restrict__ rec, Acc25& a) {
    f2 wp; wp.x = w; wp.y = w;
    float4 q[7];
    #pragma unroll
    for (int i = 0; i < 7; ++i) q[i] = ((const float4*)rec)[i];
    const f2* r2 = (const f2*)q;   // 14 packed pairs in registers
    #pragma unroll
    for (int i = 0; i < 12; ++i) {
#if __has_builtin(__builtin_elementwise_fma)
        a.p[i] = __builtin_elementwise_fma(wp, r2[i], a.p[i]);
#else
        a.p[i].x = fmaf(w, r2[i].x, a.p[i].x);
        a.p[i].y = fmaf(w, r2[i].y, a.p[i].y);
#endif
    }
    a.last = fmaf(w, q[6].x, a.last);
}

// ---------------- K0: transpose weights into fp32 [k][n] layouts in ws ----------------
__global__ __launch_bounds__(256) void k0_transpose(
    const float* __restrict__ w1, const float* __restrict__ w2, const float* __restrict__ w3,
    float* __restrict__ w1t, float* __restrict__ w2t, float* __restrict__ w3t)
{
    int idx = blockIdx.x * 256 + threadIdx.x;
    const int N1 = NIN * H;       // 655360
    const int N2 = H * H;         // 65536
    const int N3 = H * OUTP;      // 20480
    if (idx < N1) {
        int i = idx >> 8, j = idx & 255;
        w1t[idx] = w1[j * NIN + i];
    } else if (idx < N1 + N2) {
        int k = idx - N1;
        int i = k >> 8, j = k & 255;
        w2t[k] = w2[j * H + i];
    } else if (idx < N1 + N2 + N3) {
        int k = idx - N1 - N2;
        int i = k / OUTP, j = k - i * OUTP;
        w3t[k] = w3[j * H + i];
    }
}

// One LIF step, numpy-faithful per-op rounding. vth feeds ONLY the comparison,
// so decide the spike via certified interval from fast fp32 exp (~3 ulp) +
// conservative margin; exact exp_cr fallback only when |v - vth_a| <= delta
// (prob ~1e-5). Decisions provably identical (validated r17).
__device__ __forceinline__ void lif_step(float x, float bv, float& c, float& v, float& s) {
    float cn = __fadd_rn(__fadd_rn(__fmul_rn(c, 0.5f), x), bv);
    c = cn;
    float vp = v;
    float t  = __fmul_rn(__fmul_rn(vp, 0.75f), __fadd_rn(1.0f, -s));
    float vn = __fadd_rn(t, cn);
    float ag = __fdiv_rn(__fadd_rn(vp, -vn), 3.0f);
    v = vn;
    float ex_a  = __expf(ag);                       // fast f32 exp (v_exp_f32)
    float vth_a = 0.25f + 0.5f * (ex_a - 1.0f);
    float delta = 1e-5f * (ex_a + fabsf(vth_a) + 1.0f);
    if (vn > vth_a + delta) {
        s = 1.0f;
    } else if (vn < vth_a - delta) {
        s = 0.0f;
    } else {                                        // exact fallback (rare)
        float ex  = exp_cr(ag);
        float vth = __fadd_rn(0.25f, __fmul_rn(0.5f, __fadd_rn(ex, -1.0f)));
        s = (vn > vth) ? 1.0f : 0.0f;
    }
}

// write one row record: 25 spike bits as floats {0.0,1.0} + 3 pad (7 float4s)
__device__ __forceinline__ void write_rec(float* __restrict__ pairL, int pos, uint32_t m) {
    float f[RECF];
    #pragma unroll
    for (int t = 0; t < TS; ++t) f[t] = (m >> t) & 1u ? 1.0f : 0.0f;
    f[25] = 0.0f; f[26] = 0.0f; f[27] = 0.0f;
    float4* dst = (float4*)&pairL[pos * RECF];
    #pragma unroll
    for (int p = 0; p < 7; ++p)
        dst[p] = make_float4(f[4 * p], f[4 * p + 1], f[4 * p + 2], f[4 * p + 3]);
}

// ---------------- K1: fused, ONE batch row per block (2048 blocks) ----------------
// 5 blocks/CU: LDS 30,208 B x 5 = 151 KB < 160 KB; VGPR budget ~100 >> 48 used.
__global__ __launch_bounds__(256, 5) void k1_fused(
    const float* __restrict__ obs, const float* __restrict__ emean, const float* __restrict__ estd,
    const float* __restrict__ w1t, const float* __restrict__ w2t, const float* __restrict__ w3t,
    const float* __restrict__ b1, const float* __restrict__ b2, const float* __restrict__ b3,
    const float* __restrict__ dw, const float* __restrict__ db, float* __restrict__ out)
{
    __shared__ __align__(16) float pairL[256 * RECF];  // 28,672 B row records
    __shared__ __align__(16) int   idxL[256];          //  1,024 B premult indices
    __shared__ uint32_t waveCnt[4];
    __shared__ float cnt3[OUTP];

    const int tid = threadIdx.x;
    const int wave = tid >> 6, lane = tid & 63;
    const int b = blockIdx.x;
    const unsigned long long below = (1ull << lane) - 1ull;

    // ---- Phase A: population encoding, numpy-faithful fp32 op-by-op.
    // Monotonicity screen: arg < -3.23 => a < 0.0396 => 25a(1+eps) < 0.991
    // < 0.999 => mask provably 0 with NO exp call (validated r17). ----
    uint32_t msk[10];
    #pragma unroll
    for (int k = 0; k < 10; ++k) {
        int i = k * 256 + tid;
        int o = i / 10;
        float x  = obs[b * OBSD + o];
        float mu = emean[i];
        float sd = estd[i];
        float d  = __fadd_rn(x, -mu);
        float d2 = __fmul_rn(d, d);
        float nm = __fmul_rn(-0.5f, d2);
        float dn = __fmul_rn(sd, sd);
        float arg = __fdiv_rn(nm, dn);
        uint32_t m = 0;
        if (arg >= -3.23f) {
            float a  = exp_cr(arg);
            float volt = 0.0f;
            #pragma unroll
            for (int t = 0; t < TS; ++t) {
                volt = __fadd_rn(volt, a);
                if (volt > 0.999f) { m |= (1u << t); volt = __fadd_rn(volt, -0.999f); }
            }
        }
        msk[k] = m;
    }

    // ---- Phase B: event GEMM1 in two halves (<=256 active rows per half).
    // K-blocks {320 x 8} left-assoc via sorted-index boundary folds (r8-valid). ----
    Acc25 acc, part;
    acc_zero(acc); acc_zero(part);
    int nextB = 320 * H;

    for (int h = 0; h < 2; ++h) {
        // build compacted records (ascending i) for this half
        int runTot = 0;
        for (int kk = 0; kk < 5; ++kk) {
            int k = h * 5 + kk;
            uint32_t m = msk[k];
            unsigned long long bal = __ballot(m != 0u);
            if (lane == 0) waveCnt[wave] = (uint32_t)__popcll(bal);
            __syncthreads();
            int base = runTot, tot = 0;
            #pragma unroll
            for (int w = 0; w < 4; ++w) {
                if (w < wave) base += (int)waveCnt[w];
                tot += (int)waveCnt[w];
            }
            if (m) {
                int pos = base + (int)__popcll(bal & below);
                idxL[pos] = (k * 256 + tid) * H;
                write_rec(pairL, pos, m);
            }
            runTot += tot;
            __syncthreads();
        }
        const int nAct = runTot;

        // walk with STATIC 4-deep prefetch (register-resident); fma25 per row
        int pi0 = 0, pi1 = 0, pi2 = 0, pi3 = 0;
        float pw0 = 0, pw1 = 0, pw2 = 0, pw3 = 0;
        if (nAct > 0) { pi0 = rfl(idxL[0]); pw0 = w1t[pi0 + tid]; }
        if (nAct > 1) { pi1 = rfl(idxL[1]); pw1 = w1t[pi1 + tid]; }
        if (nAct > 2) { pi2 = rfl(idxL[2]); pw2 = w1t[pi2 + tid]; }
        if (nAct > 3) { pi3 = rfl(idxL[3]); pw3 = w1t[pi3 + tid]; }
        int j = 0;
        for (; j + 4 <= nAct; j += 4) {
            int ci0 = pi0, ci1 = pi1, ci2 = pi2, ci3 = pi3;
            float cw0 = pw0, cw1 = pw1, cw2 = pw2, cw3 = pw3;
            if (j + 4 < nAct) { pi0 = rfl(idxL[j + 4]); pw0 = w1t[pi0 + tid]; }
            if (j + 5 < nAct) { pi1 = rfl(idxL[j + 5]); pw1 = w1t[pi1 + tid]; }
            if (j + 6 < nAct) { pi2 = rfl(idxL[j + 6]); pw2 = w1t[pi2 + tid]; }
            if (j + 7 < nAct) { pi3 = rfl(idxL[j + 7]); pw3 = w1t[pi3 + tid]; }
            while (ci0 >= nextB) { acc_fold(acc, part); nextB += 320 * H; }
            fma25(cw0, &pairL[j * RECF], part);
            while (ci1 >= nextB) { acc_fold(acc, part); nextB += 320 * H; }
            fma25(cw1, &pairL[(j + 1) * RECF], part);
            while (ci2 >= nextB) { acc_fold(acc, part); nextB += 320 * H; }
            fma25(cw2, &pairL[(j + 2) * RECF], part);
            while (ci3 >= nextB) { acc_fold(acc, part); nextB += 320 * H; }
            fma25(cw3, &pairL[(j + 3) * RECF], part);
        }
        for (; j < nAct; ++j) {           // remainder (<=3 rows)
            int ii = rfl(idxL[j]);
            float wv = w1t[ii + tid];
            while (ii >= nextB) { acc_fold(acc, part); nextB += 320 * H; }
            fma25(wv, &pairL[j * RECF], part);
        }
        __syncthreads();   // records dead; next half (or C1 build) may overwrite
    }
    // final fold (remaining partial; empty trailing blocks are exact no-ops)
    acc_fold(acc, part);

    // ---- C1: layer-1 LIF, all 25 steps; build layer-1 spike records ----
    uint32_t m1 = 0;
    {
        float cur[TS];
        acc_unpack(acc, cur);
        const float b1v = b1[tid];
        float c1 = 0, v1 = 0, s1 = 0;
        #pragma unroll
        for (int t = 0; t < TS; ++t) {
            lif_step(cur[t], b1v, c1, v1, s1);
            if (s1 != 0.0f) m1 |= (1u << t);
        }
    }
    unsigned long long bal = __ballot(m1 != 0u);
    if (lane == 0) waveCnt[wave] = (uint32_t)__popcll(bal);
    __syncthreads();
    int base1 = 0, n1 = 0;
    #pragma unroll
    for (int w = 0; w < 4; ++w) {
        if (w < wave) base1 += (int)waveCnt[w];
        n1 += (int)waveCnt[w];
    }
    if (m1) {
        int pos = base1 + (int)__popcll(bal & below);
        idxL[pos] = tid * H;
        write_rec(pairL, pos, m1);
    }
    __syncthreads();

    // ---- C2: batched GEMM2 walk (K=256, single block) + layer-2 LIF ----
    Acc25 acc2;
    acc_zero(acc2);
    {
        int pi0 = 0, pi1 = 0, pi2 = 0, pi3 = 0;
        float pw0 = 0, pw1 = 0, pw2 = 0, pw3 = 0;
        if (n1 > 0) { pi0 = rfl(idxL[0]); pw0 = w2t[pi0 + tid]; }
        if (n1 > 1) { pi1 = rfl(idxL[1]); pw1 = w2t[pi1 + tid]; }
        if (n1 > 2) { pi2 = rfl(idxL[2]); pw2 = w2t[pi2 + tid]; }
        if (n1 > 3) { pi3 = rfl(idxL[3]); pw3 = w2t[pi3 + tid]; }
        int j = 0;
        for (; j + 4 <= n1; j += 4) {
            float cw0 = pw0, cw1 = pw1, cw2 = pw2, cw3 = pw3;
            if (j + 4 < n1) { pi0 = rfl(idxL[j + 4]); pw0 = w2t[pi0 + tid]; }
            if (j + 5 < n1) { pi1 = rfl(idxL[j + 5]); pw1 = w2t[pi1 + tid]; }
            if (j + 6 < n1) { pi2 = rfl(idxL[j + 6]); pw2 = w2t[pi2 + tid]; }
            if (j + 7 < n1) { pi3 = rfl(idxL[j + 7]); pw3 = w2t[pi3 + tid]; }
            fma25(cw0, &pairL[j * RECF], acc2);
            fma25(cw1, &pairL[(j + 1) * RECF], acc2);
            fma25(cw2, &pairL[(j + 2) * RECF], acc2);
            fma25(cw3, &pairL[(j + 3) * RECF], acc2);
        }
        for (; j < n1; ++j) {
            int ii = rfl(idxL[j]);
            fma25(w2t[ii + tid], &pairL[j * RECF], acc2);
        }
    }
    uint32_t m2 = 0;
    {
        float cur[TS];
        acc_unpack(acc2, cur);
        const float b2v = b2[tid];
        float c2 = 0, v2 = 0, s2 = 0;
        #pragma unroll
        for (int t = 0; t < TS; ++t) {
            lif_step(cur[t], b2v, c2, v2, s2);
            if (s2 != 0.0f) m2 |= (1u << t);
        }
    }
    __syncthreads();   // C2 walk reads done before list-2 build overwrites
    bal = __ballot(m2 != 0u);
    if (lane == 0) waveCnt[wave] = (uint32_t)__popcll(bal);
    __syncthreads();
    int base2 = 0, n2 = 0;
    #pragma unroll
    for (int w = 0; w < 4; ++w) {
        if (w < wave) base2 += (int)waveCnt[w];
        n2 += (int)waveCnt[w];
    }
    if (m2) {
        int pos = base2 + (int)__popcll(bal & below);
        idxL[pos] = tid * OUTP;
        write_rec(pairL, pos, m2);
    }
    __syncthreads();

    // ---- C3: batched GEMM3 walk + layer-3 LIF (threads 0..79) ----
    if (tid < OUTP) {
        Acc25 x3;
        acc_zero(x3);
        int pi0 = 0, pi1 = 0, pi2 = 0, pi3 = 0;
        float pw0 = 0, pw1 = 0, pw2 = 0, pw3 = 0;
        if (n2 > 0) { pi0 = rfl(idxL[0]); pw0 = w3t[pi0 + tid]; }
        if (n2 > 1) { pi1 = rfl(idxL[1]); pw1 = w3t[pi1 + tid]; }
        if (n2 > 2) { pi2 = rfl(idxL[2]); pw2 = w3t[pi2 + tid]; }
        if (n2 > 3) { pi3 = rfl(idxL[3]); pw3 = w3t[pi3 + tid]; }
        int j = 0;
        for (; j + 4 <= n2; j += 4) {
            float cw0 = pw0, cw1 = pw1, cw2 = pw2, cw3 = pw3;
            if (j + 4 < n2) { pi0 = rfl(idxL[j + 4]); pw0 = w3t[pi0 + tid]; }
            if (j + 5 < n2) { pi1 = rfl(idxL[j + 5]); pw1 = w3t[pi1 + tid]; }
            if (j + 6 < n2) { pi2 = rfl(idxL[j + 6]); pw2 = w3t[pi2 + tid]; }
            if (j + 7 < n2) { pi3 = rfl(idxL[j + 7]); pw3 = w3t[pi3 + tid]; }
            fma25(cw0, &pairL[j * RECF], x3);
            fma25(cw1, &pairL[(j + 1) * RECF], x3);
            fma25(cw2, &pairL[(j + 2) * RECF], x3);
            fma25(cw3, &pairL[(j + 3) * RECF], x3);
        }
        for (; j < n2; ++j) {
            int ii = rfl(idxL[j]);
            fma25(w3t[ii + tid], &pairL[j * RECF], x3);
        }
        float cur[TS];
        acc_unpack(x3, cur);
        const float b3v = b3[tid];
        float c3 = 0, v3 = 0, s3 = 0, ct = 0;
        #pragma unroll
        for (int t = 0; t < TS; ++t) {
            lif_step(cur[t], b3v, c3, v3, s3);
            ct += s3;
        }
        cnt3[tid] = ct;
    }
    __syncthreads();

    // ---- decode: per-op rounding like np einsum (no FMA) ----
    if (tid < 8) {
        float raw = 0.0f;
        #pragma unroll
        for (int pp = 0; pp < POP; ++pp) {
            float po = __fdiv_rn(cnt3[tid * POP + pp], 25.0f);
            raw = __fadd_rn(raw, __fmul_rn(po, dw[tid * POP + pp]));
        }
        raw = __fadd_rn(raw, db[tid]);
        out[b * 8 + tid] = (float)tanh((double)raw);
    }
}

extern "C" void kernel_launch(void* const* d_in, const int* in_sizes, int n_in,
                              void* d_out, int out_size, void* d_ws, size_t ws_size,
                              hipStream_t stream) {
    const float* obs   = (const float*)d_in[0];
    const float* emean = (const float*)d_in[1];
    const float* estd  = (const float*)d_in[2];
    const float* w1    = (const float*)d_in[3];
    const float* b1    = (const float*)d_in[4];
    const float* w2    = (const float*)d_in[5];
    const float* b2    = (const float*)d_in[6];
    const float* w3    = (const float*)d_in[7];
    const float* b3    = (const float*)d_in[8];
    const float* dw    = (const float*)d_in[9];
    const float* db    = (const float*)d_in[10];
    float* out = (float*)d_out;

    char* ws = (char*)d_ws;
    float* w1t = (float*)(ws);                 // 655360 * 4 = 2,621,440 B
    float* w2t = (float*)(ws + 2621440);       //  65536 * 4 =   262,144 B
    float* w3t = (float*)(ws + 2883584);       //  20480 * 4 =    81,920 B

    k0_transpose<<<2896, 256, 0, stream>>>(w1, w2, w3, w1t, w2t, w3t);
    k1_fused<<<NB, 256, 0, stream>>>(obs, emean, estd, w1t, w2t, w3t,
                                     b1, b2, b3, dw, db, out);
}